// Round 2
// baseline (8849.946 us; speedup 1.0000x reference)
//
#include <hip/hip_runtime.h>
#include <hip/hip_bf16.h>

// Bidirectional LSTM, B=32 T=512 D=512 U=512, fp32 in/out, bf16 MFMA internals.
// Phase 1: xg = x @ [Wf||Wb] + b  (bf16 MFMA GEMM, permuted columns)
// Phase 2: persistent flag-synced recurrence, 32 groups/direction, U^T in registers
// Phase 3: out = fwd + bwd

typedef __attribute__((ext_vector_type(8))) __bf16 bf16x8;
typedef __attribute__((ext_vector_type(4))) __bf16 bf16x4;
typedef __attribute__((ext_vector_type(4))) float fvec4;

#define AS_G(p) ((const __attribute__((address_space(1))) void*)(p))
#define AS_L(p) ((__attribute__((address_space(3))) void*)(p))

__device__ __forceinline__ float sigm(float x) {
  return __builtin_amdgcn_rcpf(1.f + __expf(-x));
}
__device__ __forceinline__ float tanh_f(float x) {
  return 1.f - 2.f * __builtin_amdgcn_rcpf(__expf(2.f * x) + 1.f);
}

// ---------------- conversions ----------------

__global__ void k_convert_x(const float* __restrict__ x, __bf16* __restrict__ xb) {
  size_t i = ((size_t)blockIdx.x * 256 + threadIdx.x) * 8;
  fvec4 a = *(const fvec4*)(x + i);
  fvec4 b = *(const fvec4*)(x + i + 4);
  bf16x8 o;
#pragma unroll
  for (int j = 0; j < 4; ++j) { o[j] = (__bf16)a[j]; o[4 + j] = (__bf16)b[j]; }
  *(bf16x8*)(xb + i) = o;
}

// dst[p][k] = src[k][orig(p)] as bf16. Permutation: p = g*64 + w*16 + jj*4 + gate
// <-> orig = gate*512 + g*16 + w*4 + jj  (Keras gate order i,f,c,o).
__global__ void k_build_T(const float* __restrict__ src, const float* __restrict__ bvec,
                          __bf16* __restrict__ dst, float* __restrict__ bias_out) {
  int p = blockIdx.x;
  int g = p >> 6, r = p & 63, w = r >> 4, q = r & 15, jj = q >> 2, gate = q & 3;
  int orig = gate * 512 + g * 16 + w * 4 + jj;
  for (int k = threadIdx.x; k < 512; k += 256)
    dst[(size_t)p * 512 + k] = (__bf16)src[(size_t)k * 2048 + orig];
  if (bias_out && threadIdx.x == 0) bias_out[p] = bvec[orig];
}

__global__ void k_init_flags(int* flags) {
  int i = blockIdx.x * 256 + threadIdx.x;
  if (i < 1024) flags[i] = 0;
}

// ---------------- input GEMM: [16384,512] x [4096,512]^T -> bf16 [16384,4096] ----------------

__global__ __launch_bounds__(256, 2) void k_gemm_xw(
    const __bf16* __restrict__ A,   // [16384][512] bf16
    const __bf16* __restrict__ Bt,  // [4096][512] bf16 (permuted W^T)
    const float* __restrict__ bias, // [4096] permuted
    __bf16* __restrict__ C)         // [16384][4096]
{
  __shared__ __align__(16) __bf16 As[128 * 32];
  __shared__ __align__(16) __bf16 Bs[128 * 32];
  const int tid = threadIdx.x;
  const int w = tid >> 6, lane = tid & 63, quad = lane >> 4, l15 = lane & 15;
  const int m0 = blockIdx.y * 128, n0 = blockIdx.x * 128;
  const int wm = w & 1, wn = w >> 1;

  fvec4 acc[4][4];
  const fvec4 zero = {0.f, 0.f, 0.f, 0.f};
#pragma unroll
  for (int i = 0; i < 4; ++i)
#pragma unroll
    for (int j = 0; j < 4; ++j) acc[i][j] = zero;

  for (int kb = 0; kb < 16; ++kb) {
    const int k0 = kb * 32;
#pragma unroll
    for (int i = 0; i < 2; ++i) {
      const int c = (i * 4 + w) * 64 + lane;      // 16B chunk id, 0..511
      const int row = c >> 2, kk = (c & 3) * 8;
      __builtin_amdgcn_global_load_lds(AS_G(A + (size_t)(m0 + row) * 512 + k0 + kk),
                                       AS_L(As + (size_t)(i * 4 + w) * 512), 16, 0, 0);
      __builtin_amdgcn_global_load_lds(AS_G(Bt + (size_t)(n0 + row) * 512 + k0 + kk),
                                       AS_L(Bs + (size_t)(i * 4 + w) * 512), 16, 0, 0);
    }
    __syncthreads();
    bf16x8 af[4], bfr[4];
#pragma unroll
    for (int mt = 0; mt < 4; ++mt)
      af[mt] = *(const bf16x8*)(As + (wm * 64 + mt * 16 + l15) * 32 + quad * 8);
#pragma unroll
    for (int nt = 0; nt < 4; ++nt)
      bfr[nt] = *(const bf16x8*)(Bs + (wn * 64 + nt * 16 + l15) * 32 + quad * 8);
#pragma unroll
    for (int mt = 0; mt < 4; ++mt)
#pragma unroll
      for (int nt = 0; nt < 4; ++nt)
        acc[mt][nt] = __builtin_amdgcn_mfma_f32_16x16x32_bf16(af[mt], bfr[nt], acc[mt][nt], 0, 0, 0);
    __syncthreads();
  }

#pragma unroll
  for (int nt = 0; nt < 4; ++nt) {
    const int col = n0 + wn * 64 + nt * 16 + l15;
    const float bv = bias[col];
#pragma unroll
    for (int mt = 0; mt < 4; ++mt) {
      const int rowb = m0 + wm * 64 + mt * 16 + quad * 4;
#pragma unroll
      for (int r = 0; r < 4; ++r)
        C[(size_t)(rowb + r) * 4096 + col] = (__bf16)(acc[mt][nt][r] + bv);
    }
  }
}

// ---------------- persistent recurrence ----------------
// 64 blocks: dir = blk>>5, group g = blk&31 owns h-cols [g*16, g*16+16).
// Wave w owns 16 permuted gate cols p = g*64 + w*16 + n, n = jj*4 + gate.
// Lane owns state (b = lane>>1, j0 = w*4 + (lane&1)*2), 2 columns.

__global__ __launch_bounds__(256, 1) void k_lstm_rec(
    const __bf16* __restrict__ xg,  // [16384][4096] permuted
    const float* __restrict__ z,    // [32][512]
    const __bf16* __restrict__ UT,  // [2][2048][512] permuted
    __bf16* __restrict__ hbuf,      // [2 dir][2 parity][32][512]
    float* __restrict__ outf,       // d_out [32][512][512] (fwd)
    __bf16* __restrict__ outb,      // ws [32][512][512] (bwd)
    int* __restrict__ flags)        // [2][512]
{
  const int blk = blockIdx.x, dir = blk >> 5, g = blk & 31;
  const int tid = threadIdx.x, w = tid >> 6, lane = tid & 63;
  const int quad = lane >> 4, l15 = lane & 15;
  __shared__ __align__(16) float gates[32][68];

  // U^T slice resident in registers for all 512 steps (64 VGPRs)
  bf16x8 breg[16];
  {
    const __bf16* up = UT + ((size_t)dir * 2048 + g * 64 + w * 16 + l15) * 512 + quad * 8;
#pragma unroll
    for (int ks = 0; ks < 16; ++ks) breg[ks] = *(const bf16x8*)(up + ks * 32);
  }

  const int b = lane >> 1, jpair = lane & 1;
  const int hcol = g * 16 + w * 4 + jpair * 2;
  float c0 = z[b * 512 + hcol];
  float c1 = z[b * 512 + hcol + 1];
  int* myflags = flags + dir * 512;
  const fvec4 zero = {0.f, 0.f, 0.f, 0.f};

  for (int kt = 0; kt < 512; ++kt) {
    const int t = dir ? (511 - kt) : kt;

    // prefetch xg tile (independent of h) before the flag wait
    const bf16x8 xv = *(const bf16x8*)(xg + (size_t)(b * 512 + t) * 4096 +
                                       dir * 2048 + g * 64 + w * 16 + jpair * 8);

    if (kt > 0) {
      if (tid == 0) {
        while (__hip_atomic_load(myflags + (kt - 1), __ATOMIC_RELAXED,
                                 __HIP_MEMORY_SCOPE_AGENT) < 32)
          __builtin_amdgcn_s_sleep(1);
      }
      __syncthreads();
      __builtin_amdgcn_fence(__ATOMIC_ACQUIRE, "agent");
    }

    fvec4 acc0 = zero, acc1 = zero;
    if (kt == 0) {
#pragma unroll 8
      for (int ks = 0; ks < 16; ++ks) {
        const float* zp0 = z + l15 * 512 + ks * 32 + quad * 8;
        const float* zp1 = z + (16 + l15) * 512 + ks * 32 + quad * 8;
        fvec4 f0 = *(const fvec4*)zp0, f1 = *(const fvec4*)(zp0 + 4);
        fvec4 f2 = *(const fvec4*)zp1, f3 = *(const fvec4*)(zp1 + 4);
        bf16x8 a0, a1;
#pragma unroll
        for (int j = 0; j < 4; ++j) {
          a0[j] = (__bf16)f0[j]; a0[4 + j] = (__bf16)f1[j];
          a1[j] = (__bf16)f2[j]; a1[4 + j] = (__bf16)f3[j];
        }
        acc0 = __builtin_amdgcn_mfma_f32_16x16x32_bf16(a0, breg[ks], acc0, 0, 0, 0);
        acc1 = __builtin_amdgcn_mfma_f32_16x16x32_bf16(a1, breg[ks], acc1, 0, 0, 0);
      }
    } else {
      const __bf16* hp = hbuf + ((size_t)(dir * 2 + (kt & 1)) * 32) * 512;
#pragma unroll 8
      for (int ks = 0; ks < 16; ++ks) {
        bf16x8 a0 = *(const bf16x8*)(hp + l15 * 512 + ks * 32 + quad * 8);
        bf16x8 a1 = *(const bf16x8*)(hp + (16 + l15) * 512 + ks * 32 + quad * 8);
        acc0 = __builtin_amdgcn_mfma_f32_16x16x32_bf16(a0, breg[ks], acc0, 0, 0, 0);
        acc1 = __builtin_amdgcn_mfma_f32_16x16x32_bf16(a1, breg[ks], acc1, 0, 0, 0);
      }
    }

    // transpose gates within the wave's private LDS region (cols w*16..w*16+16)
#pragma unroll
    for (int r = 0; r < 4; ++r) {
      gates[quad * 4 + r][w * 16 + l15] = acc0[r];
      gates[16 + quad * 4 + r][w * 16 + l15] = acc1[r];
    }
    const fvec4 gA = *(const fvec4*)&gates[b][w * 16 + jpair * 8];
    const fvec4 gB = *(const fvec4*)&gates[b][w * 16 + jpair * 8 + 4];

    float xf[8];
#pragma unroll
    for (int j = 0; j < 8; ++j) xf[j] = (float)xv[j];

    float ii = sigm(gA[0] + xf[0]);
    float ff = sigm(gA[1] + xf[1]);
    float cc = tanh_f(gA[2] + xf[2]);
    float oo = sigm(gA[3] + xf[3]);
    c0 = ff * c0 + ii * cc;
    const float h0 = oo * tanh_f(c0);

    ii = sigm(gB[0] + xf[4]);
    ff = sigm(gB[1] + xf[5]);
    cc = tanh_f(gB[2] + xf[6]);
    oo = sigm(gB[3] + xf[7]);
    c1 = ff * c1 + ii * cc;
    const float h1 = oo * tanh_f(c1);

    const size_t oidx = (size_t)(b * 512 + t) * 512 + hcol;
    if (dir == 0) {
      outf[oidx] = h0;
      outf[oidx + 1] = h1;
    } else {
      outb[oidx] = (__bf16)h0;
      outb[oidx + 1] = (__bf16)h1;
    }

    __bf16* hd = hbuf + ((size_t)(dir * 2 + ((kt + 1) & 1)) * 32 + b) * 512 + hcol;
    hd[0] = (__bf16)h0;
    hd[1] = (__bf16)h1;

    __threadfence();       // agent-scope release of h slice
    __syncthreads();       // all waves of this group done
    if (tid == 0)
      __hip_atomic_fetch_add(myflags + kt, 1, __ATOMIC_RELEASE, __HIP_MEMORY_SCOPE_AGENT);
  }
}

// ---------------- final merge ----------------

__global__ void k_add_bwd(float* __restrict__ out, const __bf16* __restrict__ outb) {
  size_t i = ((size_t)blockIdx.x * 256 + threadIdx.x) * 4;
  if (i >= (size_t)32 * 512 * 512) return;
  fvec4 o = *(const fvec4*)(out + i);
  bf16x4 bv = *(const bf16x4*)(outb + i);
#pragma unroll
  for (int j = 0; j < 4; ++j) o[j] += (float)bv[j];
  *(fvec4*)(out + i) = o;
}

// ---------------- host ----------------

extern "C" void kernel_launch(void* const* d_in, const int* in_sizes, int n_in,
                              void* d_out, int out_size, void* d_ws, size_t ws_size,
                              hipStream_t stream) {
  const float* x  = (const float*)d_in[0];
  const float* z  = (const float*)d_in[1];
  const float* Wf = (const float*)d_in[2];
  const float* Uf = (const float*)d_in[3];
  const float* bf = (const float*)d_in[4];
  const float* Wb = (const float*)d_in[5];
  const float* Ub = (const float*)d_in[6];
  const float* bb = (const float*)d_in[7];
  float* out = (float*)d_out;
  char* ws = (char*)d_ws;

  size_t off = 0;
  __bf16* xg    = (__bf16*)(ws + off); off += (size_t)16384 * 4096 * 2;   // 134 MB
  __bf16* UT    = (__bf16*)(ws + off); off += (size_t)2 * 2048 * 512 * 2; // 4 MB
  __bf16* hbuf  = (__bf16*)(ws + off); off += (size_t)2 * 2 * 32 * 512 * 2;
  int*    flags = (int*)(ws + off);    off += 4096;
  float*  biasp = (float*)(ws + off);  off += 4096 * 4;
  char* uni = ws + off;
  __bf16* xb   = (__bf16*)uni;                               // phase 1
  __bf16* WT   = (__bf16*)(uni + (size_t)16384 * 512 * 2);   // phase 1
  __bf16* outb = (__bf16*)uni;                               // phase 2 (aliases xb)

  k_convert_x<<<4096, 256, 0, stream>>>(x, xb);
  k_build_T<<<2048, 256, 0, stream>>>(Wf, bf, WT, biasp);
  k_build_T<<<2048, 256, 0, stream>>>(Wb, bb, WT + (size_t)2048 * 512, biasp + 2048);
  k_build_T<<<2048, 256, 0, stream>>>(Uf, nullptr, UT, nullptr);
  k_build_T<<<2048, 256, 0, stream>>>(Ub, nullptr, UT + (size_t)2048 * 512, nullptr);
  k_init_flags<<<4, 256, 0, stream>>>(flags);
  k_gemm_xw<<<dim3(32, 128), 256, 0, stream>>>(xb, WT, biasp, xg);
  k_lstm_rec<<<64, 256, 0, stream>>>(xg, z, UT, hbuf, out, outb, flags);
  k_add_bwd<<<8192, 256, 0, stream>>>(out, outb);
}

// Round 3
// 5392.924 us; speedup vs baseline: 1.6410x; 1.6410x over previous
//
#include <hip/hip_runtime.h>
#include <hip/hip_bf16.h>

// Bidirectional LSTM, B=32 T=512 D=512 U=512, fp32 in/out, bf16 MFMA internals.
// Phase 1: xg = x @ [Wf||Wb] + b  (bf16 MFMA GEMM, permuted columns)
// Phase 2: persistent flag-synced recurrence, 32 groups/direction, U^T in registers.
//          h exchange via relaxed AGENT-scope atomics (sc0/sc1 -> Infinity Cache),
//          NO agent fences in the loop (they lower to buffer_wbl2/buffer_inv = L2
//          flush+inv per step, which was 16.9us/step in R2).
// Phase 3: out = fwd + bwd

typedef __attribute__((ext_vector_type(8))) __bf16 bf16x8;
typedef __attribute__((ext_vector_type(4))) __bf16 bf16x4;
typedef __attribute__((ext_vector_type(4))) float fvec4;

#define AS_G(p) ((const __attribute__((address_space(1))) void*)(p))
#define AS_L(p) ((__attribute__((address_space(3))) void*)(p))

__device__ __forceinline__ float sigm(float x) {
  return __builtin_amdgcn_rcpf(1.f + __expf(-x));
}
__device__ __forceinline__ float tanh_f(float x) {
  return 1.f - 2.f * __builtin_amdgcn_rcpf(__expf(2.f * x) + 1.f);
}

// coherent (agent-scope, cache-bypassing) 16B h load as 2x8B relaxed atomics
__device__ __forceinline__ bf16x8 ld_h16(const __bf16* p) {
  union { unsigned long long u[2]; bf16x8 v; } cv;
  cv.u[0] = __hip_atomic_load((const unsigned long long*)p,
                              __ATOMIC_RELAXED, __HIP_MEMORY_SCOPE_AGENT);
  cv.u[1] = __hip_atomic_load((const unsigned long long*)p + 1,
                              __ATOMIC_RELAXED, __HIP_MEMORY_SCOPE_AGENT);
  return cv.v;
}

// coherent 4B h store (two packed bf16)
__device__ __forceinline__ void st_h4(__bf16* p, float h0, float h1) {
  union { __bf16 h[2]; unsigned int u; } pk;
  pk.h[0] = (__bf16)h0;
  pk.h[1] = (__bf16)h1;
  __hip_atomic_store((unsigned int*)p, pk.u, __ATOMIC_RELAXED, __HIP_MEMORY_SCOPE_AGENT);
}

// ---------------- conversions ----------------

__global__ void k_convert_x(const float* __restrict__ x, __bf16* __restrict__ xb) {
  size_t i = ((size_t)blockIdx.x * 256 + threadIdx.x) * 8;
  fvec4 a = *(const fvec4*)(x + i);
  fvec4 b = *(const fvec4*)(x + i + 4);
  bf16x8 o;
#pragma unroll
  for (int j = 0; j < 4; ++j) { o[j] = (__bf16)a[j]; o[4 + j] = (__bf16)b[j]; }
  *(bf16x8*)(xb + i) = o;
}

// dst[p][k] = src[k][orig(p)] as bf16. Permutation: p = g*64 + w*16 + jj*4 + gate
// <-> orig = gate*512 + g*16 + w*4 + jj  (Keras gate order i,f,c,o).
__global__ void k_build_T(const float* __restrict__ src, const float* __restrict__ bvec,
                          __bf16* __restrict__ dst, float* __restrict__ bias_out) {
  int p = blockIdx.x;
  int g = p >> 6, r = p & 63, w = r >> 4, q = r & 15, jj = q >> 2, gate = q & 3;
  int orig = gate * 512 + g * 16 + w * 4 + jj;
  for (int k = threadIdx.x; k < 512; k += 256)
    dst[(size_t)p * 512 + k] = (__bf16)src[(size_t)k * 2048 + orig];
  if (bias_out && threadIdx.x == 0) bias_out[p] = bvec[orig];
}

__global__ void k_init_flags(int* flags) {
  int i = blockIdx.x * 256 + threadIdx.x;
  if (i < 1024) flags[i] = 0;
}

// ---------------- input GEMM: [16384,512] x [4096,512]^T -> bf16 [16384,4096] ----------------

__global__ __launch_bounds__(256, 2) void k_gemm_xw(
    const __bf16* __restrict__ A,   // [16384][512] bf16
    const __bf16* __restrict__ Bt,  // [4096][512] bf16 (permuted W^T)
    const float* __restrict__ bias, // [4096] permuted
    __bf16* __restrict__ C)         // [16384][4096]
{
  __shared__ __align__(16) __bf16 As[128 * 32];
  __shared__ __align__(16) __bf16 Bs[128 * 32];
  const int tid = threadIdx.x;
  const int w = tid >> 6, lane = tid & 63, quad = lane >> 4, l15 = lane & 15;
  const int m0 = blockIdx.y * 128, n0 = blockIdx.x * 128;
  const int wm = w & 1, wn = w >> 1;

  fvec4 acc[4][4];
  const fvec4 zero = {0.f, 0.f, 0.f, 0.f};
#pragma unroll
  for (int i = 0; i < 4; ++i)
#pragma unroll
    for (int j = 0; j < 4; ++j) acc[i][j] = zero;

  for (int kb = 0; kb < 16; ++kb) {
    const int k0 = kb * 32;
#pragma unroll
    for (int i = 0; i < 2; ++i) {
      const int c = (i * 4 + w) * 64 + lane;      // 16B chunk id, 0..511
      const int row = c >> 2, kk = (c & 3) * 8;
      __builtin_amdgcn_global_load_lds(AS_G(A + (size_t)(m0 + row) * 512 + k0 + kk),
                                       AS_L(As + (size_t)(i * 4 + w) * 512), 16, 0, 0);
      __builtin_amdgcn_global_load_lds(AS_G(Bt + (size_t)(n0 + row) * 512 + k0 + kk),
                                       AS_L(Bs + (size_t)(i * 4 + w) * 512), 16, 0, 0);
    }
    __syncthreads();
    bf16x8 af[4], bfr[4];
#pragma unroll
    for (int mt = 0; mt < 4; ++mt)
      af[mt] = *(const bf16x8*)(As + (wm * 64 + mt * 16 + l15) * 32 + quad * 8);
#pragma unroll
    for (int nt = 0; nt < 4; ++nt)
      bfr[nt] = *(const bf16x8*)(Bs + (wn * 64 + nt * 16 + l15) * 32 + quad * 8);
#pragma unroll
    for (int mt = 0; mt < 4; ++mt)
#pragma unroll
      for (int nt = 0; nt < 4; ++nt)
        acc[mt][nt] = __builtin_amdgcn_mfma_f32_16x16x32_bf16(af[mt], bfr[nt], acc[mt][nt], 0, 0, 0);
    __syncthreads();
  }

#pragma unroll
  for (int nt = 0; nt < 4; ++nt) {
    const int col = n0 + wn * 64 + nt * 16 + l15;
    const float bv = bias[col];
#pragma unroll
    for (int mt = 0; mt < 4; ++mt) {
      const int rowb = m0 + wm * 64 + mt * 16 + quad * 4;
#pragma unroll
      for (int r = 0; r < 4; ++r)
        C[(size_t)(rowb + r) * 4096 + col] = (__bf16)(acc[mt][nt][r] + bv);
    }
  }
}

// ---------------- persistent recurrence ----------------
// 64 blocks: dir = blk>>5, group g = blk&31 owns h-cols [g*16, g*16+16).
// Wave w owns 16 permuted gate cols p = g*64 + w*16 + n, n = jj*4 + gate.
// Lane owns state (b = lane>>1, j0 = w*4 + (lane&1)*2), 2 columns.
// Sync: h through IC via relaxed agent atomics; __syncthreads drains vmcnt
// (compiler emits s_waitcnt vmcnt(0) before s_barrier) => no agent fences.

__global__ __launch_bounds__(256, 1) void k_lstm_rec(
    const __bf16* __restrict__ xg,  // [16384][4096] permuted
    const float* __restrict__ z,    // [32][512]
    const __bf16* __restrict__ UT,  // [2][2048][512] permuted
    __bf16* __restrict__ hbuf,      // [2 dir][2 parity][32][512]
    float* __restrict__ outf,       // d_out [32][512][512] (fwd)
    __bf16* __restrict__ outb,      // ws [32][512][512] (bwd)
    int* __restrict__ flags)        // [2][512]
{
  const int blk = blockIdx.x, dir = blk >> 5, g = blk & 31;
  const int tid = threadIdx.x, w = tid >> 6, lane = tid & 63;
  const int quad = lane >> 4, l15 = lane & 15;
  __shared__ __align__(16) float gates[32][68];

  // U^T slice resident in registers for all 512 steps (64 VGPRs)
  bf16x8 breg[16];
  {
    const __bf16* up = UT + ((size_t)dir * 2048 + g * 64 + w * 16 + l15) * 512 + quad * 8;
#pragma unroll
    for (int ks = 0; ks < 16; ++ks) breg[ks] = *(const bf16x8*)(up + ks * 32);
  }

  const int b = lane >> 1, jpair = lane & 1;
  const int hcol = g * 16 + w * 4 + jpair * 2;
  float c0 = z[b * 512 + hcol];
  float c1 = z[b * 512 + hcol + 1];
  int* myflags = flags + dir * 512;
  const fvec4 zero = {0.f, 0.f, 0.f, 0.f};

  for (int kt = 0; kt < 512; ++kt) {
    const int t = dir ? (511 - kt) : kt;

    // prefetch xg tile (independent of h) before the flag wait
    const bf16x8 xv = *(const bf16x8*)(xg + (size_t)(b * 512 + t) * 4096 +
                                       dir * 2048 + g * 64 + w * 16 + jpair * 8);

    if (kt > 0) {
      if (tid == 0) {
        while (__hip_atomic_load(myflags + (kt - 1), __ATOMIC_RELAXED,
                                 __HIP_MEMORY_SCOPE_AGENT) < 32)
          __builtin_amdgcn_s_sleep(1);
      }
      __syncthreads();   // barrier only; h loads below are cache-bypassing atomics
    }

    fvec4 acc0 = zero, acc1 = zero;
    if (kt == 0) {
#pragma unroll 8
      for (int ks = 0; ks < 16; ++ks) {
        const float* zp0 = z + l15 * 512 + ks * 32 + quad * 8;
        const float* zp1 = z + (16 + l15) * 512 + ks * 32 + quad * 8;
        fvec4 f0 = *(const fvec4*)zp0, f1 = *(const fvec4*)(zp0 + 4);
        fvec4 f2 = *(const fvec4*)zp1, f3 = *(const fvec4*)(zp1 + 4);
        bf16x8 a0, a1;
#pragma unroll
        for (int j = 0; j < 4; ++j) {
          a0[j] = (__bf16)f0[j]; a0[4 + j] = (__bf16)f1[j];
          a1[j] = (__bf16)f2[j]; a1[4 + j] = (__bf16)f3[j];
        }
        acc0 = __builtin_amdgcn_mfma_f32_16x16x32_bf16(a0, breg[ks], acc0, 0, 0, 0);
        acc1 = __builtin_amdgcn_mfma_f32_16x16x32_bf16(a1, breg[ks], acc1, 0, 0, 0);
      }
    } else {
      const __bf16* hp = hbuf + ((size_t)(dir * 2 + (kt & 1)) * 32) * 512;
#pragma unroll 8
      for (int ks = 0; ks < 16; ++ks) {
        bf16x8 a0 = ld_h16(hp + l15 * 512 + ks * 32 + quad * 8);
        bf16x8 a1 = ld_h16(hp + (16 + l15) * 512 + ks * 32 + quad * 8);
        acc0 = __builtin_amdgcn_mfma_f32_16x16x32_bf16(a0, breg[ks], acc0, 0, 0, 0);
        acc1 = __builtin_amdgcn_mfma_f32_16x16x32_bf16(a1, breg[ks], acc1, 0, 0, 0);
      }
    }

    // transpose gates within the wave's private LDS region (cols w*16..w*16+16)
#pragma unroll
    for (int r = 0; r < 4; ++r) {
      gates[quad * 4 + r][w * 16 + l15] = acc0[r];
      gates[16 + quad * 4 + r][w * 16 + l15] = acc1[r];
    }
    const fvec4 gA = *(const fvec4*)&gates[b][w * 16 + jpair * 8];
    const fvec4 gB = *(const fvec4*)&gates[b][w * 16 + jpair * 8 + 4];

    float xf[8];
#pragma unroll
    for (int j = 0; j < 8; ++j) xf[j] = (float)xv[j];

    float ii = sigm(gA[0] + xf[0]);
    float ff = sigm(gA[1] + xf[1]);
    float cc = tanh_f(gA[2] + xf[2]);
    float oo = sigm(gA[3] + xf[3]);
    c0 = ff * c0 + ii * cc;
    const float h0 = oo * tanh_f(c0);

    ii = sigm(gB[0] + xf[4]);
    ff = sigm(gB[1] + xf[5]);
    cc = tanh_f(gB[2] + xf[6]);
    oo = sigm(gB[3] + xf[7]);
    c1 = ff * c1 + ii * cc;
    const float h1 = oo * tanh_f(c1);

    // publish h slice first (critical path), coherent store into IC
    __bf16* hd = hbuf + ((size_t)(dir * 2 + ((kt + 1) & 1)) * 32 + b) * 512 + hcol;
    st_h4(hd, h0, h1);

    __syncthreads();   // drains vmcnt(0) -> h stores complete at coherence point
    if (tid == 0)
      __hip_atomic_fetch_add(myflags + kt, 1, __ATOMIC_RELAXED, __HIP_MEMORY_SCOPE_AGENT);

    // out stores off the critical path (drained by next step's barrier / kernel end)
    const size_t oidx = (size_t)(b * 512 + t) * 512 + hcol;
    if (dir == 0) {
      outf[oidx] = h0;
      outf[oidx + 1] = h1;
    } else {
      outb[oidx] = (__bf16)h0;
      outb[oidx + 1] = (__bf16)h1;
    }
  }
}

// ---------------- final merge ----------------

__global__ void k_add_bwd(float* __restrict__ out, const __bf16* __restrict__ outb) {
  size_t i = ((size_t)blockIdx.x * 256 + threadIdx.x) * 4;
  if (i >= (size_t)32 * 512 * 512) return;
  fvec4 o = *(const fvec4*)(out + i);
  bf16x4 bv = *(const bf16x4*)(outb + i);
#pragma unroll
  for (int j = 0; j < 4; ++j) o[j] += (float)bv[j];
  *(fvec4*)(out + i) = o;
}

// ---------------- host ----------------

extern "C" void kernel_launch(void* const* d_in, const int* in_sizes, int n_in,
                              void* d_out, int out_size, void* d_ws, size_t ws_size,
                              hipStream_t stream) {
  const float* x  = (const float*)d_in[0];
  const float* z  = (const float*)d_in[1];
  const float* Wf = (const float*)d_in[2];
  const float* Uf = (const float*)d_in[3];
  const float* bf = (const float*)d_in[4];
  const float* Wb = (const float*)d_in[5];
  const float* Ub = (const float*)d_in[6];
  const float* bb = (const float*)d_in[7];
  float* out = (float*)d_out;
  char* ws = (char*)d_ws;

  size_t off = 0;
  __bf16* xg    = (__bf16*)(ws + off); off += (size_t)16384 * 4096 * 2;   // 134 MB
  __bf16* UT    = (__bf16*)(ws + off); off += (size_t)2 * 2048 * 512 * 2; // 4 MB
  __bf16* hbuf  = (__bf16*)(ws + off); off += (size_t)2 * 2 * 32 * 512 * 2;
  int*    flags = (int*)(ws + off);    off += 4096;
  float*  biasp = (float*)(ws + off);  off += 4096 * 4;
  char* uni = ws + off;
  __bf16* xb   = (__bf16*)uni;                               // phase 1
  __bf16* WT   = (__bf16*)(uni + (size_t)16384 * 512 * 2);   // phase 1
  __bf16* outb = (__bf16*)uni;                               // phase 2 (aliases xb)

  k_convert_x<<<4096, 256, 0, stream>>>(x, xb);
  k_build_T<<<2048, 256, 0, stream>>>(Wf, bf, WT, biasp);
  k_build_T<<<2048, 256, 0, stream>>>(Wb, bb, WT + (size_t)2048 * 512, biasp + 2048);
  k_build_T<<<2048, 256, 0, stream>>>(Uf, nullptr, UT, nullptr);
  k_build_T<<<2048, 256, 0, stream>>>(Ub, nullptr, UT + (size_t)2048 * 512, nullptr);
  k_init_flags<<<4, 256, 0, stream>>>(flags);
  k_gemm_xw<<<dim3(32, 128), 256, 0, stream>>>(xb, WT, biasp, xg);
  k_lstm_rec<<<64, 256, 0, stream>>>(xg, z, UT, hbuf, out, outb, flags);
  k_add_bwd<<<8192, 256, 0, stream>>>(out, outb);
}

// Round 4
// 2266.256 us; speedup vs baseline: 3.9051x; 2.3797x over previous
//
#include <hip/hip_runtime.h>
#include <hip/hip_bf16.h>

// Bidirectional LSTM, B=32 T=512 D=512 U=512, fp32 in/out, bf16 MFMA internals.
// Phase 1: xg = x @ [Wf||Wb] + b  (bf16 MFMA GEMM, permuted columns)
// Phase 2: persistent flag-synced recurrence, 32 groups/direction, U^T in registers.
//          h exchange via relaxed AGENT-scope atomics (bypass per-XCD L2, meet at
//          Infinity Cache). R4: block-cooperative LDS staging of h (one IC round
//          trip, 16 loads in flight) instead of per-wave direct operand loads
//          (R3: VGPR-starved -> ~10 serialized RTs -> 10.1us/step).
// Phase 3: out = fwd + bwd

typedef __attribute__((ext_vector_type(8))) __bf16 bf16x8;
typedef __attribute__((ext_vector_type(4))) __bf16 bf16x4;
typedef __attribute__((ext_vector_type(4))) float fvec4;

#define AS_G(p) ((const __attribute__((address_space(1))) void*)(p))
#define AS_L(p) ((__attribute__((address_space(3))) void*)(p))

__device__ __forceinline__ float sigm(float x) {
  return __builtin_amdgcn_rcpf(1.f + __expf(-x));
}
__device__ __forceinline__ float tanh_f(float x) {
  return 1.f - 2.f * __builtin_amdgcn_rcpf(__expf(2.f * x) + 1.f);
}

// coherent 4B h store (two packed bf16), relaxed agent scope
__device__ __forceinline__ void st_h4(__bf16* p, float h0, float h1) {
  union { __bf16 h[2]; unsigned int u; } pk;
  pk.h[0] = (__bf16)h0;
  pk.h[1] = (__bf16)h1;
  __hip_atomic_store((unsigned int*)p, pk.u, __ATOMIC_RELAXED, __HIP_MEMORY_SCOPE_AGENT);
}

// ---------------- conversions ----------------

__global__ void k_convert_x(const float* __restrict__ x, __bf16* __restrict__ xb) {
  size_t i = ((size_t)blockIdx.x * 256 + threadIdx.x) * 8;
  fvec4 a = *(const fvec4*)(x + i);
  fvec4 b = *(const fvec4*)(x + i + 4);
  bf16x8 o;
#pragma unroll
  for (int j = 0; j < 4; ++j) { o[j] = (__bf16)a[j]; o[4 + j] = (__bf16)b[j]; }
  *(bf16x8*)(xb + i) = o;
}

// dst[p][k] = src[k][orig(p)] as bf16. Permutation: p = g*64 + w*16 + jj*4 + gate
// <-> orig = gate*512 + g*16 + w*4 + jj  (Keras gate order i,f,c,o).
__global__ void k_build_T(const float* __restrict__ src, const float* __restrict__ bvec,
                          __bf16* __restrict__ dst, float* __restrict__ bias_out) {
  int p = blockIdx.x;
  int g = p >> 6, r = p & 63, w = r >> 4, q = r & 15, jj = q >> 2, gate = q & 3;
  int orig = gate * 512 + g * 16 + w * 4 + jj;
  for (int k = threadIdx.x; k < 512; k += 256)
    dst[(size_t)p * 512 + k] = (__bf16)src[(size_t)k * 2048 + orig];
  if (bias_out && threadIdx.x == 0) bias_out[p] = bvec[orig];
}

__global__ void k_init_flags(int* flags) {
  int i = blockIdx.x * 256 + threadIdx.x;
  if (i < 1024) flags[i] = 0;
}

// pre-fill parity-0 h buffers (both dirs) from z in chunked layout [ks][row][32col]
__global__ void k_init_h(const float* __restrict__ z, __bf16* __restrict__ hbuf) {
  int idx = blockIdx.x * 256 + threadIdx.x;      // 0..32767
  int dir = idx >> 14, rem = idx & 16383;
  int ks = rem >> 10, row = (rem >> 5) & 31, c = rem & 31;
  hbuf[(size_t)dir * 32768 + rem] = (__bf16)z[row * 512 + ks * 32 + c];
}

// ---------------- input GEMM: [16384,512] x [4096,512]^T -> bf16 [16384,4096] ----------------

__global__ __launch_bounds__(256, 2) void k_gemm_xw(
    const __bf16* __restrict__ A,   // [16384][512] bf16
    const __bf16* __restrict__ Bt,  // [4096][512] bf16 (permuted W^T)
    const float* __restrict__ bias, // [4096] permuted
    __bf16* __restrict__ C)         // [16384][4096]
{
  __shared__ __align__(16) __bf16 As[128 * 32];
  __shared__ __align__(16) __bf16 Bs[128 * 32];
  const int tid = threadIdx.x;
  const int w = tid >> 6, lane = tid & 63, quad = lane >> 4, l15 = lane & 15;
  const int m0 = blockIdx.y * 128, n0 = blockIdx.x * 128;
  const int wm = w & 1, wn = w >> 1;

  fvec4 acc[4][4];
  const fvec4 zero = {0.f, 0.f, 0.f, 0.f};
#pragma unroll
  for (int i = 0; i < 4; ++i)
#pragma unroll
    for (int j = 0; j < 4; ++j) acc[i][j] = zero;

  for (int kb = 0; kb < 16; ++kb) {
    const int k0 = kb * 32;
#pragma unroll
    for (int i = 0; i < 2; ++i) {
      const int c = (i * 4 + w) * 64 + lane;      // 16B chunk id, 0..511
      const int row = c >> 2, kk = (c & 3) * 8;
      __builtin_amdgcn_global_load_lds(AS_G(A + (size_t)(m0 + row) * 512 + k0 + kk),
                                       AS_L(As + (size_t)(i * 4 + w) * 512), 16, 0, 0);
      __builtin_amdgcn_global_load_lds(AS_G(Bt + (size_t)(n0 + row) * 512 + k0 + kk),
                                       AS_L(Bs + (size_t)(i * 4 + w) * 512), 16, 0, 0);
    }
    __syncthreads();
    bf16x8 af[4], bfr[4];
#pragma unroll
    for (int mt = 0; mt < 4; ++mt)
      af[mt] = *(const bf16x8*)(As + (wm * 64 + mt * 16 + l15) * 32 + quad * 8);
#pragma unroll
    for (int nt = 0; nt < 4; ++nt)
      bfr[nt] = *(const bf16x8*)(Bs + (wn * 64 + nt * 16 + l15) * 32 + quad * 8);
#pragma unroll
    for (int mt = 0; mt < 4; ++mt)
#pragma unroll
      for (int nt = 0; nt < 4; ++nt)
        acc[mt][nt] = __builtin_amdgcn_mfma_f32_16x16x32_bf16(af[mt], bfr[nt], acc[mt][nt], 0, 0, 0);
    __syncthreads();
  }

#pragma unroll
  for (int nt = 0; nt < 4; ++nt) {
    const int col = n0 + wn * 64 + nt * 16 + l15;
    const float bv = bias[col];
#pragma unroll
    for (int mt = 0; mt < 4; ++mt) {
      const int rowb = m0 + wm * 64 + mt * 16 + quad * 4;
#pragma unroll
      for (int r = 0; r < 4; ++r)
        C[(size_t)(rowb + r) * 4096 + col] = (__bf16)(acc[mt][nt][r] + bv);
    }
  }
}

// ---------------- persistent recurrence ----------------
// 64 blocks: dir = blk>>5, group g = blk&31 owns h-cols [g*16, g*16+16).
// hbuf layout: [2 dir][2 parity][16 ks][32 row][32 col] bf16 (chunked for
// linear staging + conflict-optimal LDS fragment reads).
// Per step: all-threads flag poll -> 16 pipelined 8B coherent loads/lane ->
// ds_write_b128 -> barrier -> ds_read fragments + 32 MFMA -> gates -> h store
// -> barrier (vmcnt drain) -> flag add.

__global__ __launch_bounds__(256, 1) void k_lstm_rec(
    const __bf16* __restrict__ xg,  // [16384][4096] permuted
    const float* __restrict__ z,    // [32][512]
    const __bf16* __restrict__ UT,  // [2][2048][512] permuted
    __bf16* __restrict__ hbuf,      // [2][2][16384] chunked
    float* __restrict__ outf,       // d_out [32][512][512] (fwd)
    __bf16* __restrict__ outb,      // ws [32][512][512] (bwd)
    int* __restrict__ flags)        // [2][512]
{
  const int blk = blockIdx.x, dir = blk >> 5, g = blk & 31;
  const int tid = threadIdx.x, w = tid >> 6, lane = tid & 63;
  const int quad = lane >> 4, l15 = lane & 15;
  __shared__ __align__(16) __bf16 h_lds[16384];   // 32 KB, single buffer
  __shared__ __align__(16) float gates[32][68];

  // U^T slice resident in registers for all 512 steps (64 VGPRs)
  bf16x8 breg[16];
  {
    const __bf16* up = UT + ((size_t)dir * 2048 + g * 64 + w * 16 + l15) * 512 + quad * 8;
#pragma unroll
    for (int ks = 0; ks < 16; ++ks) breg[ks] = *(const bf16x8*)(up + ks * 32);
  }

  const int b = lane >> 1, jpair = lane & 1;
  const int hcol = g * 16 + w * 4 + jpair * 2;
  float c0 = z[b * 512 + hcol];
  float c1 = z[b * 512 + hcol + 1];
  int* myflags = flags + dir * 512;
  const __bf16* hsrc = hbuf + (size_t)dir * 32768;
  // producer store offset in chunked layout (elements)
  const int stoff = (g >> 1) * 1024 + b * 32 + (g & 1) * 16 + w * 4 + jpair * 2;
  // staging: this lane's linear element offset base (wave quarter)
  const int stage_off = w * 4096 + lane * 8;
  const fvec4 zero = {0.f, 0.f, 0.f, 0.f};

  for (int kt = 0; kt < 512; ++kt) {
    const int t = dir ? (511 - kt) : kt;
    const int pr = kt & 1;

    // prefetch xg tile (cached, independent of h) before the flag wait
    const bf16x8 xv = *(const bf16x8*)(xg + (size_t)(b * 512 + t) * 4096 +
                                       dir * 2048 + g * 64 + w * 16 + jpair * 8);

    if (kt > 0) {
      // every thread polls (same address -> one request per wave)
      const int* fl = myflags + (kt - 1);
      while (__hip_atomic_load(fl, __ATOMIC_RELAXED, __HIP_MEMORY_SCOPE_AGENT) < 32)
        __builtin_amdgcn_s_sleep(1);
    }

    // ---- cooperative staging: 16 independent 8B coherent loads per lane ----
    {
      const unsigned long long* src =
          (const unsigned long long*)(hsrc + pr * 16384 + stage_off);
      unsigned long long tmp[16];
#pragma unroll
      for (int it = 0; it < 8; ++it) {
        tmp[2 * it]     = __hip_atomic_load(src + it * 128,
                            __ATOMIC_RELAXED, __HIP_MEMORY_SCOPE_AGENT);
        tmp[2 * it + 1] = __hip_atomic_load(src + it * 128 + 1,
                            __ATOMIC_RELAXED, __HIP_MEMORY_SCOPE_AGENT);
      }
      __bf16* dst = h_lds + stage_off;
#pragma unroll
      for (int it = 0; it < 8; ++it) {
        union { unsigned long long u[2]; bf16x8 v; } cv;
        cv.u[0] = tmp[2 * it];
        cv.u[1] = tmp[2 * it + 1];
        *(bf16x8*)(dst + it * 512) = cv.v;
      }
    }
    __syncthreads();   // staging visible to all waves (also drains prior out-stores)

    fvec4 acc0 = zero, acc1 = zero;
#pragma unroll 8
    for (int ks = 0; ks < 16; ++ks) {
      bf16x8 a0 = *(const bf16x8*)(h_lds + ks * 1024 + l15 * 32 + quad * 8);
      bf16x8 a1 = *(const bf16x8*)(h_lds + ks * 1024 + (16 + l15) * 32 + quad * 8);
      acc0 = __builtin_amdgcn_mfma_f32_16x16x32_bf16(a0, breg[ks], acc0, 0, 0, 0);
      acc1 = __builtin_amdgcn_mfma_f32_16x16x32_bf16(a1, breg[ks], acc1, 0, 0, 0);
    }

    // transpose gates within the wave's private LDS region (cols w*16..w*16+16)
#pragma unroll
    for (int r = 0; r < 4; ++r) {
      gates[quad * 4 + r][w * 16 + l15] = acc0[r];
      gates[16 + quad * 4 + r][w * 16 + l15] = acc1[r];
    }
    const fvec4 gA = *(const fvec4*)&gates[b][w * 16 + jpair * 8];
    const fvec4 gB = *(const fvec4*)&gates[b][w * 16 + jpair * 8 + 4];

    float xf[8];
#pragma unroll
    for (int j = 0; j < 8; ++j) xf[j] = (float)xv[j];

    float ii = sigm(gA[0] + xf[0]);
    float ff = sigm(gA[1] + xf[1]);
    float cc = tanh_f(gA[2] + xf[2]);
    float oo = sigm(gA[3] + xf[3]);
    c0 = ff * c0 + ii * cc;
    const float h0 = oo * tanh_f(c0);

    ii = sigm(gB[0] + xf[4]);
    ff = sigm(gB[1] + xf[5]);
    cc = tanh_f(gB[2] + xf[6]);
    oo = sigm(gB[3] + xf[7]);
    c1 = ff * c1 + ii * cc;
    const float h1 = oo * tanh_f(c1);

    // publish h slice (critical path): coherent 4B store into next parity buffer
    st_h4(hbuf + (size_t)dir * 32768 + ((kt + 1) & 1) * 16384 + stoff, h0, h1);

    __syncthreads();   // s_waitcnt vmcnt(0) before s_barrier: h stores acked at IC
    if (tid == 0)
      __hip_atomic_fetch_add(myflags + kt, 1, __ATOMIC_RELAXED, __HIP_MEMORY_SCOPE_AGENT);

    // out stores off the critical path (drained by next step's barrier / kernel end)
    const size_t oidx = (size_t)(b * 512 + t) * 512 + hcol;
    if (dir == 0) {
      outf[oidx] = h0;
      outf[oidx + 1] = h1;
    } else {
      outb[oidx] = (__bf16)h0;
      outb[oidx + 1] = (__bf16)h1;
    }
  }
}

// ---------------- final merge ----------------

__global__ void k_add_bwd(float* __restrict__ out, const __bf16* __restrict__ outb) {
  size_t i = ((size_t)blockIdx.x * 256 + threadIdx.x) * 4;
  if (i >= (size_t)32 * 512 * 512) return;
  fvec4 o = *(const fvec4*)(out + i);
  bf16x4 bv = *(const bf16x4*)(outb + i);
#pragma unroll
  for (int j = 0; j < 4; ++j) o[j] += (float)bv[j];
  *(fvec4*)(out + i) = o;
}

// ---------------- host ----------------

extern "C" void kernel_launch(void* const* d_in, const int* in_sizes, int n_in,
                              void* d_out, int out_size, void* d_ws, size_t ws_size,
                              hipStream_t stream) {
  const float* x  = (const float*)d_in[0];
  const float* z  = (const float*)d_in[1];
  const float* Wf = (const float*)d_in[2];
  const float* Uf = (const float*)d_in[3];
  const float* bf = (const float*)d_in[4];
  const float* Wb = (const float*)d_in[5];
  const float* Ub = (const float*)d_in[6];
  const float* bb = (const float*)d_in[7];
  float* out = (float*)d_out;
  char* ws = (char*)d_ws;

  size_t off = 0;
  __bf16* xg    = (__bf16*)(ws + off); off += (size_t)16384 * 4096 * 2;   // 134 MB
  __bf16* UT    = (__bf16*)(ws + off); off += (size_t)2 * 2048 * 512 * 2; // 4 MB
  __bf16* hbuf  = (__bf16*)(ws + off); off += (size_t)2 * 2 * 16384 * 2;  // 128 KB
  int*    flags = (int*)(ws + off);    off += 4096;
  float*  biasp = (float*)(ws + off);  off += 4096 * 4;
  char* uni = ws + off;
  __bf16* xb   = (__bf16*)uni;                               // phase 1
  __bf16* WT   = (__bf16*)(uni + (size_t)16384 * 512 * 2);   // phase 1
  __bf16* outb = (__bf16*)uni;                               // phase 2 (aliases xb)

  k_convert_x<<<4096, 256, 0, stream>>>(x, xb);
  k_build_T<<<2048, 256, 0, stream>>>(Wf, bf, WT, biasp);
  k_build_T<<<2048, 256, 0, stream>>>(Wb, bb, WT + (size_t)2048 * 512, biasp + 2048);
  k_build_T<<<2048, 256, 0, stream>>>(Uf, nullptr, UT, nullptr);
  k_build_T<<<2048, 256, 0, stream>>>(Ub, nullptr, UT + (size_t)2048 * 512, nullptr);
  k_init_flags<<<4, 256, 0, stream>>>(flags);
  k_init_h<<<128, 256, 0, stream>>>(z, hbuf);
  k_gemm_xw<<<dim3(32, 128), 256, 0, stream>>>(xb, WT, biasp, xg);
  k_lstm_rec<<<64, 256, 0, stream>>>(xg, z, UT, hbuf, out, outb, flags);
  k_add_bwd<<<8192, 256, 0, stream>>>(out, outb);
}

// Round 5
// 2204.820 us; speedup vs baseline: 4.0139x; 1.0279x over previous
//
#include <hip/hip_runtime.h>
#include <hip/hip_bf16.h>

// Bidirectional LSTM, B=32 T=512 D=512 U=512, fp32 in/out, bf16 MFMA internals.
// Phase 1: xg = x @ [Wf||Wb] + b  (bf16 MFMA GEMM, permuted columns)
// Phase 2: persistent recurrence, 32 groups/direction, U^T in registers.
//          h exchange via relaxed AGENT-scope atomics (meet at Infinity Cache).
//          R5: per-consumer mailbox lines (no shared-line contention, no RMW),
//          wave0-only polling; XOR-swizzled LDS staging (conflict-free).
// Phase 3: out = fwd + bwd

typedef __attribute__((ext_vector_type(8))) __bf16 bf16x8;
typedef __attribute__((ext_vector_type(4))) __bf16 bf16x4;
typedef __attribute__((ext_vector_type(4))) float fvec4;

#define AS_G(p) ((const __attribute__((address_space(1))) void*)(p))
#define AS_L(p) ((__attribute__((address_space(3))) void*)(p))

__device__ __forceinline__ float sigm(float x) {
  return __builtin_amdgcn_rcpf(1.f + __expf(-x));
}
__device__ __forceinline__ float tanh_f(float x) {
  return 1.f - 2.f * __builtin_amdgcn_rcpf(__expf(2.f * x) + 1.f);
}

// coherent 4B h store (two packed bf16), relaxed agent scope
__device__ __forceinline__ void st_h4(__bf16* p, float h0, float h1) {
  union { __bf16 h[2]; unsigned int u; } pk;
  pk.h[0] = (__bf16)h0;
  pk.h[1] = (__bf16)h1;
  __hip_atomic_store((unsigned int*)p, pk.u, __ATOMIC_RELAXED, __HIP_MEMORY_SCOPE_AGENT);
}

// ---------------- conversions ----------------

__global__ void k_convert_x(const float* __restrict__ x, __bf16* __restrict__ xb) {
  size_t i = ((size_t)blockIdx.x * 256 + threadIdx.x) * 8;
  fvec4 a = *(const fvec4*)(x + i);
  fvec4 b = *(const fvec4*)(x + i + 4);
  bf16x8 o;
#pragma unroll
  for (int j = 0; j < 4; ++j) { o[j] = (__bf16)a[j]; o[4 + j] = (__bf16)b[j]; }
  *(bf16x8*)(xb + i) = o;
}

// dst[p][k] = src[k][orig(p)] as bf16. Permutation: p = g*64 + w*16 + jj*4 + gate
// <-> orig = gate*512 + g*16 + w*4 + jj  (Keras gate order i,f,c,o).
__global__ void k_build_T(const float* __restrict__ src, const float* __restrict__ bvec,
                          __bf16* __restrict__ dst, float* __restrict__ bias_out) {
  int p = blockIdx.x;
  int g = p >> 6, r = p & 63, w = r >> 4, q = r & 15, jj = q >> 2, gate = q & 3;
  int orig = gate * 512 + g * 16 + w * 4 + jj;
  for (int k = threadIdx.x; k < 512; k += 256)
    dst[(size_t)p * 512 + k] = (__bf16)src[(size_t)k * 2048 + orig];
  if (bias_out && threadIdx.x == 0) bias_out[p] = bvec[orig];
}

// zero the mailbox region: 2 dirs * 32 consumers * 32 producers ints
__global__ void k_init_flags(int* mbox) {
  int i = blockIdx.x * 256 + threadIdx.x;
  if (i < 2048) mbox[i] = 0;
}

// pre-fill parity-0 h buffers (both dirs) from z in chunked layout [ks][row][32col]
__global__ void k_init_h(const float* __restrict__ z, __bf16* __restrict__ hbuf) {
  int idx = blockIdx.x * 256 + threadIdx.x;      // 0..32767
  int dir = idx >> 14, rem = idx & 16383;
  int ks = rem >> 10, row = (rem >> 5) & 31, c = rem & 31;
  hbuf[(size_t)dir * 32768 + rem] = (__bf16)z[row * 512 + ks * 32 + c];
}

// ---------------- input GEMM: [16384,512] x [4096,512]^T -> bf16 [16384,4096] ----------------

__global__ __launch_bounds__(256, 2) void k_gemm_xw(
    const __bf16* __restrict__ A,   // [16384][512] bf16
    const __bf16* __restrict__ Bt,  // [4096][512] bf16 (permuted W^T)
    const float* __restrict__ bias, // [4096] permuted
    __bf16* __restrict__ C)         // [16384][4096]
{
  __shared__ __align__(16) __bf16 As[128 * 32];
  __shared__ __align__(16) __bf16 Bs[128 * 32];
  const int tid = threadIdx.x;
  const int w = tid >> 6, lane = tid & 63, quad = lane >> 4, l15 = lane & 15;
  const int m0 = blockIdx.y * 128, n0 = blockIdx.x * 128;
  const int wm = w & 1, wn = w >> 1;

  fvec4 acc[4][4];
  const fvec4 zero = {0.f, 0.f, 0.f, 0.f};
#pragma unroll
  for (int i = 0; i < 4; ++i)
#pragma unroll
    for (int j = 0; j < 4; ++j) acc[i][j] = zero;

  for (int kb = 0; kb < 16; ++kb) {
    const int k0 = kb * 32;
#pragma unroll
    for (int i = 0; i < 2; ++i) {
      const int c = (i * 4 + w) * 64 + lane;      // 16B chunk id, 0..511
      const int row = c >> 2, kk = (c & 3) * 8;
      __builtin_amdgcn_global_load_lds(AS_G(A + (size_t)(m0 + row) * 512 + k0 + kk),
                                       AS_L(As + (size_t)(i * 4 + w) * 512), 16, 0, 0);
      __builtin_amdgcn_global_load_lds(AS_G(Bt + (size_t)(n0 + row) * 512 + k0 + kk),
                                       AS_L(Bs + (size_t)(i * 4 + w) * 512), 16, 0, 0);
    }
    __syncthreads();
    bf16x8 af[4], bfr[4];
#pragma unroll
    for (int mt = 0; mt < 4; ++mt)
      af[mt] = *(const bf16x8*)(As + (wm * 64 + mt * 16 + l15) * 32 + quad * 8);
#pragma unroll
    for (int nt = 0; nt < 4; ++nt)
      bfr[nt] = *(const bf16x8*)(Bs + (wn * 64 + nt * 16 + l15) * 32 + quad * 8);
#pragma unroll
    for (int mt = 0; mt < 4; ++mt)
#pragma unroll
      for (int nt = 0; nt < 4; ++nt)
        acc[mt][nt] = __builtin_amdgcn_mfma_f32_16x16x32_bf16(af[mt], bfr[nt], acc[mt][nt], 0, 0, 0);
    __syncthreads();
  }

#pragma unroll
  for (int nt = 0; nt < 4; ++nt) {
    const int col = n0 + wn * 64 + nt * 16 + l15;
    const float bv = bias[col];
#pragma unroll
    for (int mt = 0; mt < 4; ++mt) {
      const int rowb = m0 + wm * 64 + mt * 16 + quad * 4;
#pragma unroll
      for (int r = 0; r < 4; ++r)
        C[(size_t)(rowb + r) * 4096 + col] = (__bf16)(acc[mt][nt][r] + bv);
    }
  }
}

// ---------------- persistent recurrence ----------------
// 64 blocks: dir = blk>>5, group g = blk&31 owns h-cols [g*16, g*16+16).
// hbuf (global): [2 dir][2 parity][16 ks][32 row][32 col] bf16, linear.
// h_lds (LDS): same but col-chunk XOR-swizzled: chunk' = chunk ^ ((row>>1)&3)
//   -> staging writes AND fragment reads both cover all 32 banks (conflict-free).
// Sync: mbox[dir][consumer][producer] int; producer stores kt+1 (no RMW) after
// vmcnt-drain barrier; consumer wave0 polls its own 128B line, ballot over 32 lanes.

__global__ __launch_bounds__(256, 1) void k_lstm_rec(
    const __bf16* __restrict__ xg,  // [16384][4096] permuted
    const float* __restrict__ z,    // [32][512]
    const __bf16* __restrict__ UT,  // [2][2048][512] permuted
    __bf16* __restrict__ hbuf,      // [2][2][16384] chunked
    float* __restrict__ outf,       // d_out [32][512][512] (fwd)
    __bf16* __restrict__ outb,      // ws [32][512][512] (bwd)
    int* __restrict__ mbox)         // [2][32][32]
{
  const int blk = blockIdx.x, dir = blk >> 5, g = blk & 31;
  const int tid = threadIdx.x, w = tid >> 6, lane = tid & 63;
  const int quad = lane >> 4, l15 = lane & 15;
  __shared__ __align__(16) __bf16 h_lds[16384];   // 32 KB, single buffer
  __shared__ __align__(16) float gates[32][68];

  // U^T slice resident in registers for all 512 steps (64 VGPRs)
  bf16x8 breg[16];
  {
    const __bf16* up = UT + ((size_t)dir * 2048 + g * 64 + w * 16 + l15) * 512 + quad * 8;
#pragma unroll
    for (int ks = 0; ks < 16; ++ks) breg[ks] = *(const bf16x8*)(up + ks * 32);
  }

  const int b = lane >> 1, jpair = lane & 1;
  const int hcol = g * 16 + w * 4 + jpair * 2;
  float c0 = z[b * 512 + hcol];
  float c1 = z[b * 512 + hcol + 1];
  const __bf16* hsrc = hbuf + (size_t)dir * 32768;
  // producer store offset in chunked layout (elements)
  const int stoff = (g >> 1) * 1024 + b * 32 + (g & 1) * 16 + w * 4 + jpair * 2;
  // staging: this lane's linear global element offset base (wave quarter)
  const int stage_off = w * 4096 + lane * 8;
  // LDS swizzle for staging writes (independent of it): chunk' = chunk ^ ((row>>1)&3)
  const int swz8 = ((lane & 3) ^ ((lane >> 3) & 3)) * 8;
  const int fr_swz = ((l15 >> 1) & 3);  // fragment-read XOR term (same for row, row+16)
  int* my_line = mbox + dir * 1024 + g * 32;         // consumer line (poll)
  int* my_col  = mbox + dir * 1024 + lane * 32 + g;  // producer slots (store, lane<32)
  const fvec4 zero = {0.f, 0.f, 0.f, 0.f};

  for (int kt = 0; kt < 512; ++kt) {
    const int t = dir ? (511 - kt) : kt;
    const int pr = kt & 1;

    // prefetch xg tile (cached, independent of h) before the wait
    const bf16x8 xv = *(const bf16x8*)(xg + (size_t)(b * 512 + t) * 4096 +
                                       dir * 2048 + g * 64 + w * 16 + jpair * 8);

    if (kt > 0) {
      if (w == 0) {
        const int* mb = my_line + (lane & 31);
        for (;;) {
          int v = __hip_atomic_load(mb, __ATOMIC_RELAXED, __HIP_MEMORY_SCOPE_AGENT);
          if (!__ballot(lane < 32 && v < kt)) break;
          __builtin_amdgcn_s_sleep(1);
        }
      }
      __syncthreads();   // releases waves 1-3 once h(kt-1) fully published
    }

    // ---- cooperative staging: 16 independent 8B coherent loads per lane ----
    {
      const unsigned long long* src =
          (const unsigned long long*)(hsrc + pr * 16384 + stage_off);
      unsigned long long tmp[16];
#pragma unroll
      for (int it = 0; it < 8; ++it) {
        tmp[2 * it]     = __hip_atomic_load(src + it * 128,
                            __ATOMIC_RELAXED, __HIP_MEMORY_SCOPE_AGENT);
        tmp[2 * it + 1] = __hip_atomic_load(src + it * 128 + 1,
                            __ATOMIC_RELAXED, __HIP_MEMORY_SCOPE_AGENT);
      }
#pragma unroll
      for (int it = 0; it < 8; ++it) {
        union { unsigned long long u[2]; bf16x8 v; } cv;
        cv.u[0] = tmp[2 * it];
        cv.u[1] = tmp[2 * it + 1];
        // dst: ks = w*4 + it/2, row = (it&1)*16 + lane/4, chunk' swizzled
        *(bf16x8*)(h_lds + (w * 4 + (it >> 1)) * 1024 +
                   ((it & 1) * 16 + (lane >> 2)) * 32 + swz8) = cv.v;
      }
    }
    __syncthreads();   // staging visible to all waves

    fvec4 acc0 = zero, acc1 = zero;
#pragma unroll 8
    for (int ks = 0; ks < 16; ++ks) {
      bf16x8 a0 = *(const bf16x8*)(h_lds + ks * 1024 + l15 * 32 +
                                   ((quad ^ fr_swz) * 8));
      bf16x8 a1 = *(const bf16x8*)(h_lds + ks * 1024 + (16 + l15) * 32 +
                                   ((quad ^ fr_swz) * 8));
      acc0 = __builtin_amdgcn_mfma_f32_16x16x32_bf16(a0, breg[ks], acc0, 0, 0, 0);
      acc1 = __builtin_amdgcn_mfma_f32_16x16x32_bf16(a1, breg[ks], acc1, 0, 0, 0);
    }

    // transpose gates within the wave's private LDS region (cols w*16..w*16+16)
#pragma unroll
    for (int r = 0; r < 4; ++r) {
      gates[quad * 4 + r][w * 16 + l15] = acc0[r];
      gates[16 + quad * 4 + r][w * 16 + l15] = acc1[r];
    }
    const fvec4 gA = *(const fvec4*)&gates[b][w * 16 + jpair * 8];
    const fvec4 gB = *(const fvec4*)&gates[b][w * 16 + jpair * 8 + 4];

    float xf[8];
#pragma unroll
    for (int j = 0; j < 8; ++j) xf[j] = (float)xv[j];

    float ii = sigm(gA[0] + xf[0]);
    float ff = sigm(gA[1] + xf[1]);
    float cc = tanh_f(gA[2] + xf[2]);
    float oo = sigm(gA[3] + xf[3]);
    c0 = ff * c0 + ii * cc;
    const float h0 = oo * tanh_f(c0);

    ii = sigm(gB[0] + xf[4]);
    ff = sigm(gB[1] + xf[5]);
    cc = tanh_f(gB[2] + xf[6]);
    oo = sigm(gB[3] + xf[7]);
    c1 = ff * c1 + ii * cc;
    const float h1 = oo * tanh_f(c1);

    // publish h slice (critical path): coherent 4B store into next parity buffer
    st_h4(hbuf + (size_t)dir * 32768 + ((kt + 1) & 1) * 16384 + stoff, h0, h1);

    __syncthreads();   // s_waitcnt vmcnt(0) before s_barrier: h stores acked at IC
    if (w == 0 && lane < 32)
      __hip_atomic_store(my_col, kt + 1, __ATOMIC_RELAXED, __HIP_MEMORY_SCOPE_AGENT);

    // out stores off the critical path (drained by next step's barrier / kernel end)
    const size_t oidx = (size_t)(b * 512 + t) * 512 + hcol;
    if (dir == 0) {
      outf[oidx] = h0;
      outf[oidx + 1] = h1;
    } else {
      outb[oidx] = (__bf16)h0;
      outb[oidx + 1] = (__bf16)h1;
    }
  }
}

// ---------------- final merge ----------------

__global__ void k_add_bwd(float* __restrict__ out, const __bf16* __restrict__ outb) {
  size_t i = ((size_t)blockIdx.x * 256 + threadIdx.x) * 4;
  if (i >= (size_t)32 * 512 * 512) return;
  fvec4 o = *(const fvec4*)(out + i);
  bf16x4 bv = *(const bf16x4*)(outb + i);
#pragma unroll
  for (int j = 0; j < 4; ++j) o[j] += (float)bv[j];
  *(fvec4*)(out + i) = o;
}

// ---------------- host ----------------

extern "C" void kernel_launch(void* const* d_in, const int* in_sizes, int n_in,
                              void* d_out, int out_size, void* d_ws, size_t ws_size,
                              hipStream_t stream) {
  const float* x  = (const float*)d_in[0];
  const float* z  = (const float*)d_in[1];
  const float* Wf = (const float*)d_in[2];
  const float* Uf = (const float*)d_in[3];
  const float* bf = (const float*)d_in[4];
  const float* Wb = (const float*)d_in[5];
  const float* Ub = (const float*)d_in[6];
  const float* bb = (const float*)d_in[7];
  float* out = (float*)d_out;
  char* ws = (char*)d_ws;

  size_t off = 0;
  __bf16* xg    = (__bf16*)(ws + off); off += (size_t)16384 * 4096 * 2;   // 134 MB
  __bf16* UT    = (__bf16*)(ws + off); off += (size_t)2 * 2048 * 512 * 2; // 4 MB
  __bf16* hbuf  = (__bf16*)(ws + off); off += (size_t)2 * 2 * 16384 * 2;  // 128 KB
  int*    mbox  = (int*)(ws + off);    off += 8192;                       // 2*32*32 ints
  float*  biasp = (float*)(ws + off);  off += 4096 * 4;
  char* uni = ws + off;
  __bf16* xb   = (__bf16*)uni;                               // phase 1
  __bf16* WT   = (__bf16*)(uni + (size_t)16384 * 512 * 2);   // phase 1
  __bf16* outb = (__bf16*)uni;                               // phase 2 (aliases xb)

  k_convert_x<<<4096, 256, 0, stream>>>(x, xb);
  k_build_T<<<2048, 256, 0, stream>>>(Wf, bf, WT, biasp);
  k_build_T<<<2048, 256, 0, stream>>>(Wb, bb, WT + (size_t)2048 * 512, biasp + 2048);
  k_build_T<<<2048, 256, 0, stream>>>(Uf, nullptr, UT, nullptr);
  k_build_T<<<2048, 256, 0, stream>>>(Ub, nullptr, UT + (size_t)2048 * 512, nullptr);
  k_init_flags<<<8, 256, 0, stream>>>(mbox);
  k_init_h<<<128, 256, 0, stream>>>(z, hbuf);
  k_gemm_xw<<<dim3(32, 128), 256, 0, stream>>>(xb, WT, biasp, xg);
  k_lstm_rec<<<64, 256, 0, stream>>>(xg, z, UT, hbuf, out, outb, mbox);
  k_add_bwd<<<8192, 256, 0, stream>>>(out, outb);
}